// Round 16
// baseline (113.342 us; speedup 1.0000x reference)
//
#include <hip/hip_runtime.h>
#include <math.h>
#include <stdint.h>

#define LSEQ 256
#define HD 256

typedef float floatx4 __attribute__((ext_vector_type(4)));

__device__ __forceinline__ float dot4(float4 a, float4 b) {
    return a.x * b.x + a.y * b.y + a.z * b.z + a.w * b.w;
}
__device__ __forceinline__ float4 ldnt4(const float* p) {
    floatx4 r = __builtin_nontemporal_load((const floatx4*)p);
    return make_float4(r.x, r.y, r.z, r.w);
}

// ---- 4-row batch loads (NT for HBM one-shot streams, plain for L2) ----
#define LOAD4NT(R, base, kk) do { _Pragma("unroll") \
    for (int j = 0; j < 4; ++j) R[j] = ldnt4((base) + (size_t)((kk) + j) * HD + le4); } while (0)
#define LOAD4P(R, base, kk) do { _Pragma("unroll") \
    for (int j = 0; j < 4; ++j) R[j] = *(const float4*)((base) + (size_t)((kk) + j) * HD + le4); } while (0)

// ---- consume variants ----
#define CONS4_K1(R, kk) do { _Pragma("unroll") \
    for (int j = 0; j < 4; ++j) { \
        float s = dot4(q4, R[j]); \
        s += __shfl_xor(s, 1); s += __shfl_xor(s, 2); \
        s += __shfl_xor(s, 4); s += __shfl_xor(s, 8); \
        if ((lane & 15) == 0) scK[head][(kk) + j] = s; } } while (0)
#define CONS4_K2(R, kk) do { _Pragma("unroll") \
    for (int j = 0; j < 4; ++j) { \
        float s = dot4(q4, R[j]); \
        s += __shfl_xor(s, 1); s += __shfl_xor(s, 2); \
        s += __shfl_xor(s, 4); s += __shfl_xor(s, 8); \
        if ((lane & 15) == 0) sc[head][(kk) + j] = (s + scK[head][(kk) + j]) * 0.125f; } } while (0)
#define CONS4_V(R, kk) do { _Pragma("unroll") \
    for (int j = 0; j < 4; ++j) { \
        float a = sc[head][(kk) + j]; \
        acc.x += a * R[j].x; acc.y += a * R[j].y; \
        acc.z += a * R[j].z; acc.w += a * R[j].w; } } while (0)
#define CONS4_S(R, kk) do { _Pragma("unroll") \
    for (int j = 0; j < 4; ++j) { \
        acc.x += R[j].x; acc.y += R[j].y; acc.z += R[j].z; acc.w += R[j].w; } } while (0)

// ---- rolling two-batch (4+4 rows) pipeline over [r0v, rendv), guarded ----
#define PIPE4(LOADM, CONSM, CONS1, base, r0v, rendv) do { \
    if ((rendv) > (r0v)) { \
        int nfull_ = ((rendv) - (r0v)) & ~7; \
        int kend8_ = (r0v) + nfull_; \
        float4 A_[4], B_[4]; \
        if (nfull_ >= 8) { \
            LOADM(A_, base, (r0v)); LOADM(B_, base, (r0v) + 4); \
            int k_ = (r0v); \
            for (; k_ + 16 <= kend8_; k_ += 8) { \
                CONSM(A_, k_);     LOADM(A_, base, k_ + 8); \
                CONSM(B_, k_ + 4); LOADM(B_, base, k_ + 12); \
            } \
            CONSM(A_, k_); CONSM(B_, k_ + 4); \
        } \
        for (int k_ = kend8_; k_ < (rendv); ++k_) { \
            float4 T_ = *(const float4*)((base) + (size_t)k_ * HD + le4); \
            CONS1(T_, k_); \
        } \
    } } while (0)

#define CONS1_K1(T, kk) do { \
    float s = dot4(q4, T); \
    s += __shfl_xor(s, 1); s += __shfl_xor(s, 2); \
    s += __shfl_xor(s, 4); s += __shfl_xor(s, 8); \
    if ((lane & 15) == 0) scK[head][kk] = s; } while (0)
#define CONS1_K2(T, kk) do { \
    float s = dot4(q4, T); \
    s += __shfl_xor(s, 1); s += __shfl_xor(s, 2); \
    s += __shfl_xor(s, 4); s += __shfl_xor(s, 8); \
    if ((lane & 15) == 0) sc[head][kk] = (s + scK[head][kk]) * 0.125f; } while (0)
#define CONS1_V(T, kk) do { \
    float a = sc[head][kk]; \
    acc.x += a * T.x; acc.y += a * T.y; acc.z += a * T.z; acc.w += a * T.w; } while (0)
#define CONS1_S(T, kk) do { \
    acc.x += T.x; acc.y += T.y; acc.z += T.z; acc.w += T.w; } while (0)

// ---------------- 1. projections + abs_pos fold ----------------
__global__ __launch_bounds__(256) void proj_kernel(
    const float* __restrict__ queries, const float* __restrict__ keys,
    const float* __restrict__ values,
    const float* __restrict__ apK, const float* __restrict__ apV,
    const float* __restrict__ Wq, const float* __restrict__ bq,
    const float* __restrict__ Wk, const float* __restrict__ bk,
    const float* __restrict__ Wv, const float* __restrict__ bv,
    float* __restrict__ Qo, float* __restrict__ Ko, float* __restrict__ Vo)
{
    const int R = 4;
    int tid = threadIdx.x;
    int row0 = blockIdx.x * R;

    float aq[R] = {0.f, 0.f, 0.f, 0.f};
    float ak[R] = {0.f, 0.f, 0.f, 0.f};
    float av[R] = {0.f, 0.f, 0.f, 0.f};

    const float* wq = Wq + tid * HD;
    const float* wk = Wk + tid * HD;
    const float* wv = Wv + tid * HD;

    #pragma unroll 2
    for (int i = 0; i < HD; i += 4) {
        float4 wq4 = *(const float4*)(wq + i);
        float4 wk4 = *(const float4*)(wk + i);
        float4 wv4 = *(const float4*)(wv + i);
        #pragma unroll
        for (int r = 0; r < R; ++r) {
            float4 xq = *(const float4*)(queries + (row0 + r) * HD + i);
            float4 xk = *(const float4*)(keys    + (row0 + r) * HD + i);
            float4 xv = *(const float4*)(values  + (row0 + r) * HD + i);
            aq[r] += dot4(xq, wq4);
            ak[r] += dot4(xk, wk4);
            av[r] += dot4(xv, wv4);
        }
    }
    #pragma unroll
    for (int r = 0; r < R; ++r) {
        int idx = (row0 + r) * HD + tid;
        Qo[idx] = aq[r] + bq[tid];
        Ko[idx] = ak[r] + bk[tid] + apK[idx];
        Vo[idx] = av[r] + bv[tid] + apV[idx];
    }
}

// ---------------- 1b. per-batch mean of Veff (masked rows) ----------
__global__ __launch_bounds__(256) void vmean_kernel(
    const float* __restrict__ Veff, float* __restrict__ Vm)
{
    int b = blockIdx.x;
    int t = threadIdx.x;
    const float* Vb = Veff + b * (LSEQ * HD);
    float s = 0.f;
    #pragma unroll 4
    for (int k = 0; k < LSEQ; ++k)
        s += Vb[k * HD + t];
    Vm[b * HD + t] = s * (1.0f / 256.0f);
}

// ---------------- 2. fused attention ----------------
// One block per bq (LPT: q descending). 512 thr = 8 waves; wave w owns a
// contiguous k-run. 4-row A/B pipeline keeps VGPR <= 85 so 3 blocks/CU
// co-reside (24 waves/CU, +50% over the 8-row version) — occupancy probe.
__global__ __launch_bounds__(512, 6) void attn_kernel(
    const float* __restrict__ Q, const float* __restrict__ Keff,
    const float* __restrict__ Veff, const float* __restrict__ tK,
    const float* __restrict__ tV, const float* __restrict__ Vm,
    const int* __restrict__ tmask, float* __restrict__ out)
{
    __shared__ float scK[4][260];
    __shared__ float sc[4][260];
    __shared__ float outp[8][256];

    int bid = blockIdx.x;
    int q = 255 - (bid >> 2);       // heavy rows first (LPT)
    int b = bid & 3;
    int bq = (b << 8) | q;

    int tid = threadIdx.x;
    int w = tid >> 6;
    int lane = tid & 63;
    int head = lane >> 4;
    int le4 = lane * 4;

    bool masked = tmask[bq] != 0;   // whole row NEG -> exactly uniform attn

    const float* tVr = tV + (size_t)bq * (LSEQ * HD);
    float4 acc = make_float4(0.f, 0.f, 0.f, 0.f);

    if (masked) {
        // pure tV stream: out = (sum_k tV[k]) / 256 + Vmean
        int r0 = w * 32;
        int rend = r0 + 32;
        PIPE4(LOAD4NT, CONS4_S, CONS1_S, tVr, r0, rend);
    } else {
        const float* tKr = tK + (size_t)bq * (LSEQ * HD);
        const float* Kb  = Keff + b * (LSEQ * HD);
        const float* Vb  = Veff + b * (LSEQ * HD);
        float4 q4 = *(const float4*)(Q + bq * HD + le4);

        int nk = q + 1;                 // causal: k <= q (rest exact 0)
        int run = (nk + 7) >> 3;
        int r0 = min(w * run, nk);
        int rend = min(r0 + run, nk);

        // phase 1: scK = Q.Keff (L2 GEMV; same-wave range, no barrier needed)
        PIPE4(LOAD4P, CONS4_K1, CONS1_K1, Kb, r0, rend);
        // phase 2: pure tK stream -> final scores
        PIPE4(LOAD4NT, CONS4_K2, CONS1_K2, tKr, r0, rend);
        __syncthreads();

        // phase 3: softmax (wave w<4 handles head w)
        if (w < 4) {
            int k0 = lane * 4;
            float4 vv = *(const float4*)(&sc[w][k0]);
            float x0 = (k0 + 0 <= q) ? vv.x : -INFINITY;
            float x1 = (k0 + 1 <= q) ? vv.y : -INFINITY;
            float x2 = (k0 + 2 <= q) ? vv.z : -INFINITY;
            float x3 = (k0 + 3 <= q) ? vv.w : -INFINITY;
            float m = fmaxf(fmaxf(x0, x1), fmaxf(x2, x3));
            #pragma unroll
            for (int off = 32; off >= 1; off >>= 1)
                m = fmaxf(m, __shfl_xor(m, off));
            float e0 = __expf(x0 - m);
            float e1 = __expf(x1 - m);
            float e2 = __expf(x2 - m);
            float e3 = __expf(x3 - m);
            float ssum = e0 + e1 + e2 + e3;
            #pragma unroll
            for (int off = 32; off >= 1; off >>= 1)
                ssum += __shfl_xor(ssum, off);
            float inv = 1.0f / ssum;
            *(float4*)(&sc[w][k0]) = make_float4(e0 * inv, e1 * inv,
                                                 e2 * inv, e3 * inv);
        }
        __syncthreads();

        // phase 4: pure tV stream, weighted
        PIPE4(LOAD4NT, CONS4_V, CONS1_V, tVr, r0, rend);
        // phase 5: Veff GEMV (L2), weighted
        PIPE4(LOAD4P, CONS4_V, CONS1_V, Vb, r0, rend);
    }

    *(float4*)(&outp[w][le4]) = acc;
    __syncthreads();
    if (tid < 256) {
        float o = 0.f;
        #pragma unroll
        for (int p = 0; p < 8; ++p) o += outp[p][tid];
        if (masked) o = o * (1.0f / 256.0f) + Vm[b * HD + tid];
        out[(size_t)bq * HD + tid] = o;
    }
}

extern "C" void kernel_launch(void* const* d_in, const int* in_sizes, int n_in,
                              void* d_out, int out_size, void* d_ws, size_t ws_size,
                              hipStream_t stream) {
    const float* queries = (const float*)d_in[0];
    const float* keys    = (const float*)d_in[1];
    const float* values  = (const float*)d_in[2];
    const float* tK      = (const float*)d_in[3];
    const float* tV      = (const float*)d_in[4];
    const float* apK     = (const float*)d_in[5];
    const float* apV     = (const float*)d_in[6];
    const int*   tmask   = (const int*)d_in[7];
    // d_in[8] future_time_mask: analytic (k > q), never read
    const float* Wq = (const float*)d_in[9];
    const float* bq = (const float*)d_in[10];
    const float* Wk = (const float*)d_in[11];
    const float* bk = (const float*)d_in[12];
    const float* Wv = (const float*)d_in[13];
    const float* bv = (const float*)d_in[14];

    float* ws = (float*)d_ws;
    float* Qo = ws;                     // [1024][256]
    float* Ko = ws + 262144;            // Keff = K + bk + pK
    float* Vo = ws + 524288;            // Veff = V + bv + pV
    float* Vm = ws + 786432;            // [4][256]
    float* out = (float*)d_out;

    proj_kernel<<<256, 256, 0, stream>>>(queries, keys, values, apK, apV,
                                         Wq, bq, Wk, bk, Wv, bv, Qo, Ko, Vo);
    vmean_kernel<<<4, 256, 0, stream>>>(Vo, Vm);
    attn_kernel<<<1024, 512, 0, stream>>>(Qo, Ko, Vo, tK, tV, Vm, tmask, out);
}

// Round 17
// 102.752 us; speedup vs baseline: 1.1031x; 1.1031x over previous
//
#include <hip/hip_runtime.h>
#include <math.h>
#include <stdint.h>

#define LSEQ 256
#define HD 256

typedef float floatx4 __attribute__((ext_vector_type(4)));

__device__ __forceinline__ float dot4(float4 a, float4 b) {
    return a.x * b.x + a.y * b.y + a.z * b.z + a.w * b.w;
}
__device__ __forceinline__ float4 ldnt4(const float* p) {
    floatx4 r = __builtin_nontemporal_load((const floatx4*)p);
    return make_float4(r.x, r.y, r.z, r.w);
}

// ---- 8-row batch load (NT for HBM one-shot streams, plain for L2) ----
#define LOAD8NT(R, base, kk) do { _Pragma("unroll") \
    for (int j = 0; j < 8; ++j) R[j] = ldnt4((base) + (size_t)((kk) + j) * HD + le4); } while (0)
#define LOAD8P(R, base, kk) do { _Pragma("unroll") \
    for (int j = 0; j < 8; ++j) R[j] = *(const float4*)((base) + (size_t)((kk) + j) * HD + le4); } while (0)

// ---- consume variants ----
#define CONS8_K1(R, kk) do { _Pragma("unroll") \
    for (int j = 0; j < 8; ++j) { \
        float s = dot4(q4, R[j]); \
        s += __shfl_xor(s, 1); s += __shfl_xor(s, 2); \
        s += __shfl_xor(s, 4); s += __shfl_xor(s, 8); \
        if ((lane & 15) == 0) scK[head][(kk) + j] = s; } } while (0)
#define CONS8_K2(R, kk) do { _Pragma("unroll") \
    for (int j = 0; j < 8; ++j) { \
        float s = dot4(q4, R[j]); \
        s += __shfl_xor(s, 1); s += __shfl_xor(s, 2); \
        s += __shfl_xor(s, 4); s += __shfl_xor(s, 8); \
        if ((lane & 15) == 0) sc[head][(kk) + j] = (s + scK[head][(kk) + j]) * 0.125f; } } while (0)
#define CONS8_V(R, kk) do { _Pragma("unroll") \
    for (int j = 0; j < 8; ++j) { \
        float a = sc[head][(kk) + j]; \
        acc.x += a * R[j].x; acc.y += a * R[j].y; \
        acc.z += a * R[j].z; acc.w += a * R[j].w; } } while (0)
#define CONS8_S(R, kk) do { _Pragma("unroll") \
    for (int j = 0; j < 8; ++j) { \
        acc.x += R[j].x; acc.y += R[j].y; acc.z += R[j].z; acc.w += R[j].w; } } while (0)

// ---- two-batch software pipeline over k-range [r0v, rendv) (n <= 32) ----
#define PIPE(LOADM, CONSM, CONS1, base, r0v, rendv) do { \
    int n_ = (rendv) > (r0v) ? (rendv) - (r0v) : 0; \
    int k_ = (r0v); \
    float4 A_[8], B_[8]; \
    if (n_ >= 8) { \
        LOADM(A_, base, k_); \
        if (n_ >= 16) { \
            LOADM(B_, base, k_ + 8); CONSM(A_, k_); \
            if (n_ >= 24) { \
                LOADM(A_, base, k_ + 16); CONSM(B_, k_ + 8); \
                if (n_ >= 32) { \
                    LOADM(B_, base, k_ + 24); CONSM(A_, k_ + 16); CONSM(B_, k_ + 24); \
                } else { CONSM(A_, k_ + 16); } \
            } else { CONSM(B_, k_ + 8); } \
        } else { CONSM(A_, k_); } \
        k_ += (n_ & ~7); \
    } \
    for (int jj = 0; jj < (n_ & 7); ++jj, ++k_) { \
        float4 T_ = *(const float4*)((base) + (size_t)k_ * HD + le4); \
        CONS1(T_, k_); \
    } } while (0)

#define CONS1_K1(T, kk) do { \
    float s = dot4(q4, T); \
    s += __shfl_xor(s, 1); s += __shfl_xor(s, 2); \
    s += __shfl_xor(s, 4); s += __shfl_xor(s, 8); \
    if ((lane & 15) == 0) scK[head][kk] = s; } while (0)
#define CONS1_K2(T, kk) do { \
    float s = dot4(q4, T); \
    s += __shfl_xor(s, 1); s += __shfl_xor(s, 2); \
    s += __shfl_xor(s, 4); s += __shfl_xor(s, 8); \
    if ((lane & 15) == 0) sc[head][kk] = (s + scK[head][kk]) * 0.125f; } while (0)
#define CONS1_V(T, kk) do { \
    float a = sc[head][kk]; \
    acc.x += a * T.x; acc.y += a * T.y; acc.z += a * T.z; acc.w += a * T.w; } while (0)
#define CONS1_S(T, kk) do { \
    acc.x += T.x; acc.y += T.y; acc.z += T.z; acc.w += T.w; } while (0)

// ---------------- 1. projections + abs_pos fold ----------------
__global__ __launch_bounds__(256) void proj_kernel(
    const float* __restrict__ queries, const float* __restrict__ keys,
    const float* __restrict__ values,
    const float* __restrict__ apK, const float* __restrict__ apV,
    const float* __restrict__ Wq, const float* __restrict__ bq,
    const float* __restrict__ Wk, const float* __restrict__ bk,
    const float* __restrict__ Wv, const float* __restrict__ bv,
    float* __restrict__ Qo, float* __restrict__ Ko, float* __restrict__ Vo)
{
    const int R = 4;
    int tid = threadIdx.x;
    int row0 = blockIdx.x * R;

    float aq[R] = {0.f, 0.f, 0.f, 0.f};
    float ak[R] = {0.f, 0.f, 0.f, 0.f};
    float av[R] = {0.f, 0.f, 0.f, 0.f};

    const float* wq = Wq + tid * HD;
    const float* wk = Wk + tid * HD;
    const float* wv = Wv + tid * HD;

    #pragma unroll 2
    for (int i = 0; i < HD; i += 4) {
        float4 wq4 = *(const float4*)(wq + i);
        float4 wk4 = *(const float4*)(wk + i);
        float4 wv4 = *(const float4*)(wv + i);
        #pragma unroll
        for (int r = 0; r < R; ++r) {
            float4 xq = *(const float4*)(queries + (row0 + r) * HD + i);
            float4 xk = *(const float4*)(keys    + (row0 + r) * HD + i);
            float4 xv = *(const float4*)(values  + (row0 + r) * HD + i);
            aq[r] += dot4(xq, wq4);
            ak[r] += dot4(xk, wk4);
            av[r] += dot4(xv, wv4);
        }
    }
    #pragma unroll
    for (int r = 0; r < R; ++r) {
        int idx = (row0 + r) * HD + tid;
        Qo[idx] = aq[r] + bq[tid];
        Ko[idx] = ak[r] + bk[tid] + apK[idx];
        Vo[idx] = av[r] + bv[tid] + apV[idx];
    }
}

// ---------------- 1b. per-batch mean of Veff (masked rows) ----------
__global__ __launch_bounds__(256) void vmean_kernel(
    const float* __restrict__ Veff, float* __restrict__ Vm)
{
    int b = blockIdx.x;
    int t = threadIdx.x;
    const float* Vb = Veff + b * (LSEQ * HD);
    float s = 0.f;
    #pragma unroll 4
    for (int k = 0; k < LSEQ; ++k)
        s += Vb[k * HD + t];
    Vm[b * HD + t] = s * (1.0f / 256.0f);
}

// ---------------- 2. fused attention ----------------
// One block per bq (LPT: q descending). 512 thr = 8 waves; wave w owns a
// contiguous k-run. HBM streams (tK, tV) are PURE (no L2 loads interleaved)
// and two-batch pipelined (16KB in flight/wave); Keff/Veff are L2 GEMVs.
__global__ __launch_bounds__(512, 2) void attn_kernel(
    const float* __restrict__ Q, const float* __restrict__ Keff,
    const float* __restrict__ Veff, const float* __restrict__ tK,
    const float* __restrict__ tV, const float* __restrict__ Vm,
    const int* __restrict__ tmask, float* __restrict__ out)
{
    __shared__ float scK[4][260];
    __shared__ float sc[4][260];
    __shared__ float outp[8][256];

    int bid = blockIdx.x;
    int q = 255 - (bid >> 2);       // heavy rows first (LPT)
    int b = bid & 3;
    int bq = (b << 8) | q;

    int tid = threadIdx.x;
    int w = tid >> 6;
    int lane = tid & 63;
    int head = lane >> 4;
    int le4 = lane * 4;

    bool masked = tmask[bq] != 0;   // whole row NEG -> exactly uniform attn

    const float* tVr = tV + (size_t)bq * (LSEQ * HD);
    float4 acc = make_float4(0.f, 0.f, 0.f, 0.f);

    if (masked) {
        // pure tV stream: out = (sum_k tV[k]) / 256 + Vmean
        int r0 = w * 32;
        PIPE(LOAD8NT, CONS8_S, CONS1_S, tVr, r0, r0 + 32);
    } else {
        const float* tKr = tK + (size_t)bq * (LSEQ * HD);
        const float* Kb  = Keff + b * (LSEQ * HD);
        const float* Vb  = Veff + b * (LSEQ * HD);
        float4 q4 = *(const float4*)(Q + bq * HD + le4);

        int nk = q + 1;                 // causal: k <= q (rest exact 0)
        int run = (nk + 7) >> 3;
        int r0 = w * run;
        int rend = min(r0 + run, nk);

        // phase 1: scK = Q.Keff (L2 GEMV; same-wave range, no barrier needed)
        PIPE(LOAD8P, CONS8_K1, CONS1_K1, Kb, r0, rend);
        // phase 2: pure tK stream -> final scores
        PIPE(LOAD8NT, CONS8_K2, CONS1_K2, tKr, r0, rend);
        __syncthreads();

        // phase 3: softmax (wave w<4 handles head w)
        if (w < 4) {
            int k0 = lane * 4;
            float4 vv = *(const float4*)(&sc[w][k0]);
            float x0 = (k0 + 0 <= q) ? vv.x : -INFINITY;
            float x1 = (k0 + 1 <= q) ? vv.y : -INFINITY;
            float x2 = (k0 + 2 <= q) ? vv.z : -INFINITY;
            float x3 = (k0 + 3 <= q) ? vv.w : -INFINITY;
            float m = fmaxf(fmaxf(x0, x1), fmaxf(x2, x3));
            #pragma unroll
            for (int off = 32; off >= 1; off >>= 1)
                m = fmaxf(m, __shfl_xor(m, off));
            float e0 = __expf(x0 - m);
            float e1 = __expf(x1 - m);
            float e2 = __expf(x2 - m);
            float e3 = __expf(x3 - m);
            float ssum = e0 + e1 + e2 + e3;
            #pragma unroll
            for (int off = 32; off >= 1; off >>= 1)
                ssum += __shfl_xor(ssum, off);
            float inv = 1.0f / ssum;
            *(float4*)(&sc[w][k0]) = make_float4(e0 * inv, e1 * inv,
                                                 e2 * inv, e3 * inv);
        }
        __syncthreads();

        // phase 4: pure tV stream, weighted
        PIPE(LOAD8NT, CONS8_V, CONS1_V, tVr, r0, rend);
        // phase 5: Veff GEMV (L2), weighted
        PIPE(LOAD8P, CONS8_V, CONS1_V, Vb, r0, rend);
    }

    *(float4*)(&outp[w][le4]) = acc;
    __syncthreads();
    if (tid < 256) {
        float o = 0.f;
        #pragma unroll
        for (int p = 0; p < 8; ++p) o += outp[p][tid];
        if (masked) o = o * (1.0f / 256.0f) + Vm[b * HD + tid];
        out[(size_t)bq * HD + tid] = o;
    }
}

extern "C" void kernel_launch(void* const* d_in, const int* in_sizes, int n_in,
                              void* d_out, int out_size, void* d_ws, size_t ws_size,
                              hipStream_t stream) {
    const float* queries = (const float*)d_in[0];
    const float* keys    = (const float*)d_in[1];
    const float* values  = (const float*)d_in[2];
    const float* tK      = (const float*)d_in[3];
    const float* tV      = (const float*)d_in[4];
    const float* apK     = (const float*)d_in[5];
    const float* apV     = (const float*)d_in[6];
    const int*   tmask   = (const int*)d_in[7];
    // d_in[8] future_time_mask: analytic (k > q), never read
    const float* Wq = (const float*)d_in[9];
    const float* bq = (const float*)d_in[10];
    const float* Wk = (const float*)d_in[11];
    const float* bk = (const float*)d_in[12];
    const float* Wv = (const float*)d_in[13];
    const float* bv = (const float*)d_in[14];

    float* ws = (float*)d_ws;
    float* Qo = ws;                     // [1024][256]
    float* Ko = ws + 262144;            // Keff = K + bk + pK
    float* Vo = ws + 524288;            // Veff = V + bv + pV
    float* Vm = ws + 786432;            // [4][256]
    float* out = (float*)d_out;

    proj_kernel<<<256, 256, 0, stream>>>(queries, keys, values, apK, apV,
                                         Wq, bq, Wk, bk, Wv, bv, Qo, Ko, Vo);
    vmean_kernel<<<4, 256, 0, stream>>>(Vo, Vm);
    attn_kernel<<<1024, 512, 0, stream>>>(Qo, Ko, Vo, tK, tV, Vm, tmask, out);
}